// Round 6
// baseline (321.739 us; speedup 1.0000x reference)
//
#include <hip/hip_runtime.h>

// Fused CircularBoundaryBlock:
//   out = relu(LN(x + W2 @ relu(W1 @ [roll(x,1), x, roll(x,-1)] + b1) + b2))
// B=4, N=65536, H=128, fp32 I/O, bf16 MFMA internally.
//
// v7 = v6 + LN-direct epilogue (no vs buffer).
//   Bank-math audit showed v6's access phases are already near-uniform; the
//   SQ_LDS_BANK_CONFLICT counter is dominated by inherent b128 multi-phase
//   cycles. Remaining levers = LDS op count + barrier count. So: LayerNorm
//   now runs directly on the acc2 registers:
//     - per-lane partial (s, sum v^2) over its 8 cols (VALU only)
//     - 4x float2 partial writes to ps2[64][18] (9 KB) + ONE barrier
//     - read 16 partials/row (8 aligned b128), mu/rsig, redistribute to the
//       rt dimension via 8 ds_bpermute (__shfl from lane (l, g=rt))
//     - normalize in-reg with gamma/beta PRELOADED IN REGISTERS, store f32x4
//       straight to global (64B segments per g-quad -> HBM-granule friendly)
//   Removes: 8 b128 vs-writes + 8 b128 vs-reads + 16 b128 gamma/beta reads
//   + one barrier per iter, and the vs/xs aliasing constraint.
// Everything else identical to v6: W1 frags in regs, W2 frags in LDS (32KB),
// swapped-operand MFMA, T14 stage split + halo prefetch, setprio,
// 256 thr, 512 blocks, 2 blocks/CU.

typedef __bf16 bf16x8 __attribute__((ext_vector_type(8)));
typedef __bf16 bf16x4 __attribute__((ext_vector_type(4)));
typedef float  f32x4  __attribute__((ext_vector_type(4)));

#define H      128
#define NB     65536        // rows per batch
#define TILE   64
#define XS     136          // x LDS stride (bf16 elems)
#define HSS    136          // h LDS stride (bf16 elems)
#define PSS    18           // ps2 stride (float2), 144 B: 16B-aligned rows, odd*4 words
#define NTILES 4096         // 4 * 65536 / 64
#define GRID   512          // 2 blocks/CU * 256 CUs

__global__ __launch_bounds__(256, 2)
void cbb_kernel(const float* __restrict__ x, const float* __restrict__ W1,
                const float* __restrict__ b1, const float* __restrict__ W2,
                const float* __restrict__ b2, const float* __restrict__ gamma,
                const float* __restrict__ beta, float* __restrict__ out) {
    // xs (66*136 bf16) + hs (64*136 bf16) = 35360 B (no vs buffer anymore)
    __shared__ __align__(16) char raw[(66 * XS + 64 * HSS) * 2];
    __bf16* xs = (__bf16*)raw;
    __bf16* hs = xs + 66 * XS;
    __shared__ __align__(16) __bf16 w2s[16384];   // W2 frags, 32 KB, persistent
    __shared__ __align__(16) float2 ps2[64 * PSS]; // LN partials, 9216 B

    const int tid  = threadIdx.x;
    const int wid  = tid >> 6;
    const int lane = tid & 63;
    const int l    = lane & 15;   // MFMA n index (tile row, after swap)
    const int g    = lane >> 4;   // MFMA quad
    const int col0 = wid * 32;

    // per-lane bias + gamma/beta quads: output cols col0 + ct*16 + g*4 .. +3
    const f32x4 b1v[2] = { *(const f32x4*)(b1 + col0 + g * 4),
                           *(const f32x4*)(b1 + col0 + 16 + g * 4) };
    const f32x4 b2v[2] = { *(const f32x4*)(b2 + col0 + g * 4),
                           *(const f32x4*)(b2 + col0 + 16 + g * 4) };
    const f32x4 gmv[2] = { *(const f32x4*)(gamma + col0 + g * 4),
                           *(const f32x4*)(gamma + col0 + 16 + g * 4) };
    const f32x4 btv[2] = { *(const f32x4*)(beta + col0 + g * 4),
                           *(const f32x4*)(beta + col0 + 16 + g * 4) };

    // ---- W1 B-fragments persistent in registers (this wave's 32-col slice) ----
    bf16x8 w1f[12][2];
#pragma unroll
    for (int ks = 0; ks < 12; ++ks) {
#pragma unroll
        for (int ct = 0; ct < 2; ++ct) {
            const int cc = col0 + ct * 16 + l;
            bf16x8 f;
#pragma unroll
            for (int j = 0; j < 8; ++j)
                f[j] = (__bf16)W1[(ks * 32 + g * 8 + j) * H + cc];
            w1f[ks][ct] = f;
        }
    }

    // ---- W2 B-fragments -> LDS, fragment-ordered (once per block) ----
    // layout: w2s[w*4096 + ks*1024 + ct*512 + lane*8 + j]
    for (int idx = tid; idx < 16384; idx += 256) {
        const int j  = idx & 7;
        const int ln = (idx >> 3) & 63;
        const int ct = (idx >> 9) & 1;
        const int ks = (idx >> 10) & 3;
        const int w  = idx >> 12;
        const int row = ks * 32 + (ln >> 4) * 8 + j;
        const int col = w * 32 + ct * 16 + (ln & 15);
        w2s[idx] = (__bf16)W2[row * H + col];
    }
    const __bf16* w2w = w2s + wid * 4096;

    // ---- T14 prefetch: full 66-row halo tile (8 float4 + tid<64 halo) ----
    float4 xreg[8];
    float4 xhalo;
    {
        const int t  = blockIdx.x;
        const int b  = t >> 10;
        const int n0 = (t & 1023) << 6;
        const size_t rowbase = (size_t)b * NB;
#pragma unroll
        for (int s = 0; s < 8; ++s) {
            const int q = tid + s * 256;            // q < 2048 -> rows 0..63
            const int r = q >> 5, c = q & 31;
            const int grow = (n0 - 1 + r + NB) & (NB - 1);
            xreg[s] = *(const float4*)(x + ((rowbase + grow) * H + c * 4));
        }
        if (tid < 64) {                              // rows 64,65
            const int q = 2048 + tid;
            const int r = q >> 5, c = q & 31;
            const int grow = (n0 - 1 + r + NB) & (NB - 1);
            xhalo = *(const float4*)(x + ((rowbase + grow) * H + c * 4));
        }
    }

    for (int t = blockIdx.x; t < NTILES; t += GRID) {
        const int b  = t >> 10;
        const int n0 = (t & 1023) << 6;
        const size_t rowbase = (size_t)b * NB;

        __syncthreads();  // B1: all prev-iter xs/hs/ps2 readers done

        // ---- stage: consume prefetched regs -> xs (bf16) ----
#pragma unroll
        for (int s = 0; s < 8; ++s) {
            const int q = tid + s * 256;
            const int r = q >> 5, c = q & 31;
            bf16x4 v4;
            v4[0] = (__bf16)xreg[s].x; v4[1] = (__bf16)xreg[s].y;
            v4[2] = (__bf16)xreg[s].z; v4[3] = (__bf16)xreg[s].w;
            *(bf16x4*)(xs + r * XS + c * 4) = v4;
        }
        if (tid < 64) {
            const int q = 2048 + tid;
            const int r = q >> 5, c = q & 31;
            bf16x4 v4;
            v4[0] = (__bf16)xhalo.x; v4[1] = (__bf16)xhalo.y;
            v4[2] = (__bf16)xhalo.z; v4[3] = (__bf16)xhalo.w;
            *(bf16x4*)(xs + r * XS + c * 4) = v4;
        }
        __syncthreads();  // B2: xs tile visible

        // ---- issue next tile's loads; they fly under GEMM1/GEMM2/LN ----
        if (t + GRID < NTILES) {
            const int tn  = t + GRID;
            const int bn  = tn >> 10;
            const int n0n = (tn & 1023) << 6;
            const size_t rbn = (size_t)bn * NB;
#pragma unroll
            for (int s = 0; s < 8; ++s) {
                const int q = tid + s * 256;
                const int r = q >> 5, c = q & 31;
                const int grow = (n0n - 1 + r + NB) & (NB - 1);
                xreg[s] = *(const float4*)(x + ((rbn + grow) * H + c * 4));
            }
            if (tid < 64) {
                const int q = 2048 + tid;
                const int r = q >> 5, c = q & 31;
                const int grow = (n0n - 1 + r + NB) & (NB - 1);
                xhalo = *(const float4*)(x + ((rbn + grow) * H + c * 4));
            }
        }

        // ---- GEMM1 (swapped): acc[rt][ct] = D[hcol quad][tilerow] ----
        f32x4 acc[4][2];
#pragma unroll
        for (int rt = 0; rt < 4; ++rt)
#pragma unroll
            for (int ct = 0; ct < 2; ++ct)
                acc[rt][ct] = (f32x4){0.f, 0.f, 0.f, 0.f};

        __builtin_amdgcn_s_setprio(1);
#pragma unroll
        for (int ks = 0; ks < 12; ++ks) {
            const int k  = ks * 32 + g * 8;          // k in [0,384)
            const int ro = k >> 7, kc = k & 127;
#pragma unroll
            for (int rt = 0; rt < 4; ++rt) {
                const bf16x8 a = *(const bf16x8*)(xs + (rt * 16 + l + ro) * XS + kc);
                acc[rt][0] = __builtin_amdgcn_mfma_f32_16x16x32_bf16(w1f[ks][0], a, acc[rt][0], 0, 0, 0);
                acc[rt][1] = __builtin_amdgcn_mfma_f32_16x16x32_bf16(w1f[ks][1], a, acc[rt][1], 0, 0, 0);
            }
        }
        __builtin_amdgcn_s_setprio(0);

        // relu + bias -> hs: lane holds cols col0+ct*16+g*4..+3 of row rt*16+l
#pragma unroll
        for (int rt = 0; rt < 4; ++rt) {
#pragma unroll
            for (int ct = 0; ct < 2; ++ct) {
                bf16x4 hv;
#pragma unroll
                for (int i = 0; i < 4; ++i)
                    hv[i] = (__bf16)fmaxf(acc[rt][ct][i] + b1v[ct][i], 0.f);
                *(bf16x4*)(hs + (rt * 16 + l) * HSS + col0 + ct * 16 + g * 4) = hv;
            }
        }
        __syncthreads();  // B3: hs tile visible

        // ---- GEMM2 (swapped): delta[outcol quad][tilerow] ----
        f32x4 acc2[4][2];
#pragma unroll
        for (int rt = 0; rt < 4; ++rt)
#pragma unroll
            for (int ct = 0; ct < 2; ++ct)
                acc2[rt][ct] = (f32x4){0.f, 0.f, 0.f, 0.f};

        __builtin_amdgcn_s_setprio(1);
#pragma unroll
        for (int ks = 0; ks < 4; ++ks) {
            const bf16x8 wf0 = *(const bf16x8*)(w2w + ks * 1024 + lane * 8);
            const bf16x8 wf1 = *(const bf16x8*)(w2w + ks * 1024 + 512 + lane * 8);
#pragma unroll
            for (int rt = 0; rt < 4; ++rt) {
                const bf16x8 a = *(const bf16x8*)(hs + (rt * 16 + l) * HSS + ks * 32 + g * 8);
                acc2[rt][0] = __builtin_amdgcn_mfma_f32_16x16x32_bf16(wf0, a, acc2[rt][0], 0, 0, 0);
                acc2[rt][1] = __builtin_amdgcn_mfma_f32_16x16x32_bf16(wf1, a, acc2[rt][1], 0, 0, 0);
            }
        }
        __builtin_amdgcn_s_setprio(0);

        // ---- residual: v = x + delta + b2 (vectorized b64 x re-read) ----
#pragma unroll
        for (int rt = 0; rt < 4; ++rt) {
#pragma unroll
            for (int ct = 0; ct < 2; ++ct) {
                const bf16x4 xv = *(const bf16x4*)(xs + (rt * 16 + l + 1) * XS + col0 + ct * 16 + g * 4);
#pragma unroll
                for (int i = 0; i < 4; ++i)
                    acc2[rt][ct][i] += b2v[ct][i] + (float)xv[i];
            }
        }

        // ---- LN partials: per-lane (s, sum v^2) over its 8 cols, per rt ----
#pragma unroll
        for (int rt = 0; rt < 4; ++rt) {
            float s = 0.f, qq = 0.f;
#pragma unroll
            for (int ct = 0; ct < 2; ++ct)
#pragma unroll
                for (int i = 0; i < 4; ++i) {
                    const float v = acc2[rt][ct][i];
                    s += v; qq += v * v;
                }
            ps2[(rt * 16 + l) * PSS + wid * 4 + g] = make_float2(s, qq);
        }
        __syncthreads();  // B4: partials visible (also orders next ps2 write)

        // ---- row stats for assigned row ar = g*16+l, then bpermute to rt ----
        float mu, rv;
        {
            const int ar = g * 16 + l;
            const f32x4* pp = (const f32x4*)(ps2 + ar * PSS);  // 144B-aligned
            float S = 0.f, Q = 0.f;
#pragma unroll
            for (int j = 0; j < 8; ++j) {
                const f32x4 e = pp[j];   // [s0,q0,s1,q1]
                S += e[0] + e[2];
                Q += e[1] + e[3];
            }
            mu = S * (1.f / 128.f);
            const float var = Q * (1.f / 128.f) - mu * mu;
            rv = rsqrtf(var + 1e-5f);
        }

        // ---- normalize + relu in-reg, store f32x4 direct to global ----
#pragma unroll
        for (int rt = 0; rt < 4; ++rt) {
            const float mur = __shfl(mu, (lane & 15) + rt * 16);
            const float rvr = __shfl(rv, (lane & 15) + rt * 16);
            float* op = out + (rowbase + n0 + rt * 16 + l) * H + col0;
#pragma unroll
            for (int ct = 0; ct < 2; ++ct) {
                f32x4 o;
#pragma unroll
                for (int i = 0; i < 4; ++i)
                    o[i] = fmaxf((acc2[rt][ct][i] - mur) * rvr * gmv[ct][i] + btv[ct][i], 0.f);
                *(f32x4*)(op + ct * 16 + g * 4) = o;
            }
        }
    }
}

extern "C" void kernel_launch(void* const* d_in, const int* in_sizes, int n_in,
                              void* d_out, int out_size, void* d_ws, size_t ws_size,
                              hipStream_t stream) {
    const float* x     = (const float*)d_in[0];
    const float* W1    = (const float*)d_in[1];
    const float* b1    = (const float*)d_in[2];
    const float* W2    = (const float*)d_in[3];
    const float* b2    = (const float*)d_in[4];
    const float* gamma = (const float*)d_in[5];
    const float* beta  = (const float*)d_in[6];
    float* out = (float*)d_out;

    // 512 blocks = 2 resident blocks/CU * 256 CUs; grid-stride over 4096 tiles
    cbb_kernel<<<GRID, 256, 0, stream>>>(x, W1, b1, W2, b2, gamma, beta, out);
}

// Round 7
// 260.592 us; speedup vs baseline: 1.2346x; 1.2346x over previous
//
#include <hip/hip_runtime.h>

// Fused CircularBoundaryBlock:
//   out = relu(LN(x + W2 @ relu(W1 @ [roll(x,1), x, roll(x,-1)] + b1) + b2))
// B=4, N=65536, H=128, fp32 I/O, bf16 MFMA internally.
//
// v8 = v7 (LN-direct epilogue, no vs buffer) with the spill fixed.
//   v7's counters showed scratch round-trips (+46/+85 MB FETCH/WRITE): the
//   epilogue live set (~150 VGPR-class) blew the 128 arch-VGPR half of the
//   file (weights hold the AGPR half). v8 reclaims ~64 regs:
//     - b1/b2/gamma/beta quads now live in tiny LDS arrays (2 KB) and are
//       read as ONE aligned b128 at each use site, not held persistently.
//     - LN partial reads accumulate 2x f32x4 at a time (was pp[8] = 32 regs).
//     - barrier audit: loop-top barrier is redundant once vs is gone (B4
//       orders all prev-iter xs/hs readers) -> 3 barriers/iter (was 5 in v6).
//   Kept from v7: swapped-operand MFMA epilogues, ps2 f32 partials + one
//   barrier + bpermute stats redistribution, direct f32x4 global store in
//   MFMA layout (128B-line aligned per wave), T14 stage split + halo
//   prefetch, W1 frags in regs, W2 frags in LDS, setprio.
// LDS total ~79.4 KB -> still 2 blocks/CU. 256 thr, 512 blocks.

typedef __bf16 bf16x8 __attribute__((ext_vector_type(8)));
typedef __bf16 bf16x4 __attribute__((ext_vector_type(4)));
typedef float  f32x4  __attribute__((ext_vector_type(4)));

#define H      128
#define NB     65536        // rows per batch
#define TILE   64
#define XS     136          // x LDS stride (bf16 elems)
#define HSS    136          // h LDS stride (bf16 elems)
#define PSS    18           // ps2 stride (float2), 144 B: 16B-aligned rows
#define NTILES 4096         // 4 * 65536 / 64
#define GRID   512          // 2 blocks/CU * 256 CUs

__global__ __launch_bounds__(256, 2)
void cbb_kernel(const float* __restrict__ x, const float* __restrict__ W1,
                const float* __restrict__ b1, const float* __restrict__ W2,
                const float* __restrict__ b2, const float* __restrict__ gamma,
                const float* __restrict__ beta, float* __restrict__ out) {
    // xs (66*136 bf16) + hs (64*136 bf16) = 35360 B (no vs buffer)
    __shared__ __align__(16) char raw[(66 * XS + 64 * HSS) * 2];
    __bf16* xs = (__bf16*)raw;
    __bf16* hs = xs + 66 * XS;
    __shared__ __align__(16) __bf16 w2s[16384];    // W2 frags, 32 KB, persistent
    __shared__ __align__(16) float2 ps2[64 * PSS]; // LN partials, 9216 B
    __shared__ __align__(16) float s_b1[128], s_b2[128], s_gamma[128], s_beta[128];

    const int tid  = threadIdx.x;
    const int wid  = tid >> 6;
    const int lane = tid & 63;
    const int l    = lane & 15;   // MFMA n index (tile row, after swap)
    const int g    = lane >> 4;   // MFMA quad
    const int col0 = wid * 32;

    if (tid < 128) {
        s_b1[tid] = b1[tid];   s_b2[tid]   = b2[tid];
        s_gamma[tid] = gamma[tid]; s_beta[tid] = beta[tid];
    }

    // ---- W1 B-fragments persistent in registers (this wave's 32-col slice) ----
    bf16x8 w1f[12][2];
#pragma unroll
    for (int ks = 0; ks < 12; ++ks) {
#pragma unroll
        for (int ct = 0; ct < 2; ++ct) {
            const int cc = col0 + ct * 16 + l;
            bf16x8 f;
#pragma unroll
            for (int j = 0; j < 8; ++j)
                f[j] = (__bf16)W1[(ks * 32 + g * 8 + j) * H + cc];
            w1f[ks][ct] = f;
        }
    }

    // ---- W2 B-fragments -> LDS, fragment-ordered (once per block) ----
    // layout: w2s[w*4096 + ks*1024 + ct*512 + lane*8 + j]
    for (int idx = tid; idx < 16384; idx += 256) {
        const int j  = idx & 7;
        const int ln = (idx >> 3) & 63;
        const int ct = (idx >> 9) & 1;
        const int ks = (idx >> 10) & 3;
        const int w  = idx >> 12;
        const int row = ks * 32 + (ln >> 4) * 8 + j;
        const int col = w * 32 + ct * 16 + (ln & 15);
        w2s[idx] = (__bf16)W2[row * H + col];
    }
    const __bf16* w2w = w2s + wid * 4096;

    // ---- T14 prefetch: full 66-row halo tile (8 float4 + tid<64 halo) ----
    float4 xreg[8];
    float4 xhalo;
    {
        const int t  = blockIdx.x;
        const int b  = t >> 10;
        const int n0 = (t & 1023) << 6;
        const size_t rowbase = (size_t)b * NB;
#pragma unroll
        for (int s = 0; s < 8; ++s) {
            const int q = tid + s * 256;            // q < 2048 -> rows 0..63
            const int r = q >> 5, c = q & 31;
            const int grow = (n0 - 1 + r + NB) & (NB - 1);
            xreg[s] = *(const float4*)(x + ((rowbase + grow) * H + c * 4));
        }
        if (tid < 64) {                              // rows 64,65
            const int q = 2048 + tid;
            const int r = q >> 5, c = q & 31;
            const int grow = (n0 - 1 + r + NB) & (NB - 1);
            xhalo = *(const float4*)(x + ((rowbase + grow) * H + c * 4));
        }
    }

    for (int t = blockIdx.x; t < NTILES; t += GRID) {
        const int b  = t >> 10;
        const int n0 = (t & 1023) << 6;
        const size_t rowbase = (size_t)b * NB;

        // NOTE: no loop-top barrier needed — prev-iter xs/hs readers are all
        // ordered before B4(ps2); post-B4 work touches only ps2 + global.

        // ---- stage: consume prefetched regs -> xs (bf16) ----
#pragma unroll
        for (int s = 0; s < 8; ++s) {
            const int q = tid + s * 256;
            const int r = q >> 5, c = q & 31;
            bf16x4 v4;
            v4[0] = (__bf16)xreg[s].x; v4[1] = (__bf16)xreg[s].y;
            v4[2] = (__bf16)xreg[s].z; v4[3] = (__bf16)xreg[s].w;
            *(bf16x4*)(xs + r * XS + c * 4) = v4;
        }
        if (tid < 64) {
            const int q = 2048 + tid;
            const int r = q >> 5, c = q & 31;
            bf16x4 v4;
            v4[0] = (__bf16)xhalo.x; v4[1] = (__bf16)xhalo.y;
            v4[2] = (__bf16)xhalo.z; v4[3] = (__bf16)xhalo.w;
            *(bf16x4*)(xs + r * XS + c * 4) = v4;
        }
        __syncthreads();  // B2: xs tile visible

        // ---- issue next tile's loads; they fly under GEMM1/GEMM2/LN ----
        if (t + GRID < NTILES) {
            const int tn  = t + GRID;
            const int bn  = tn >> 10;
            const int n0n = (tn & 1023) << 6;
            const size_t rbn = (size_t)bn * NB;
#pragma unroll
            for (int s = 0; s < 8; ++s) {
                const int q = tid + s * 256;
                const int r = q >> 5, c = q & 31;
                const int grow = (n0n - 1 + r + NB) & (NB - 1);
                xreg[s] = *(const float4*)(x + ((rbn + grow) * H + c * 4));
            }
            if (tid < 64) {
                const int q = 2048 + tid;
                const int r = q >> 5, c = q & 31;
                const int grow = (n0n - 1 + r + NB) & (NB - 1);
                xhalo = *(const float4*)(x + ((rbn + grow) * H + c * 4));
            }
        }

        // ---- GEMM1 (swapped): acc[rt][ct] = D[hcol quad][tilerow] ----
        f32x4 acc[4][2];
#pragma unroll
        for (int rt = 0; rt < 4; ++rt)
#pragma unroll
            for (int ct = 0; ct < 2; ++ct)
                acc[rt][ct] = (f32x4){0.f, 0.f, 0.f, 0.f};

        __builtin_amdgcn_s_setprio(1);
#pragma unroll
        for (int ks = 0; ks < 12; ++ks) {
            const int k  = ks * 32 + g * 8;          // k in [0,384)
            const int ro = k >> 7, kc = k & 127;
#pragma unroll
            for (int rt = 0; rt < 4; ++rt) {
                const bf16x8 a = *(const bf16x8*)(xs + (rt * 16 + l + ro) * XS + kc);
                acc[rt][0] = __builtin_amdgcn_mfma_f32_16x16x32_bf16(w1f[ks][0], a, acc[rt][0], 0, 0, 0);
                acc[rt][1] = __builtin_amdgcn_mfma_f32_16x16x32_bf16(w1f[ks][1], a, acc[rt][1], 0, 0, 0);
            }
        }
        __builtin_amdgcn_s_setprio(0);

        // relu + bias -> hs: lane holds cols col0+ct*16+g*4..+3 of row rt*16+l
        {
            const f32x4 b1q0 = *(const f32x4*)(s_b1 + col0 + g * 4);
            const f32x4 b1q1 = *(const f32x4*)(s_b1 + col0 + 16 + g * 4);
#pragma unroll
            for (int rt = 0; rt < 4; ++rt) {
                bf16x4 h0, h1;
#pragma unroll
                for (int i = 0; i < 4; ++i) {
                    h0[i] = (__bf16)fmaxf(acc[rt][0][i] + b1q0[i], 0.f);
                    h1[i] = (__bf16)fmaxf(acc[rt][1][i] + b1q1[i], 0.f);
                }
                *(bf16x4*)(hs + (rt * 16 + l) * HSS + col0 + g * 4)      = h0;
                *(bf16x4*)(hs + (rt * 16 + l) * HSS + col0 + 16 + g * 4) = h1;
            }
        }
        __syncthreads();  // B3: hs tile visible

        // ---- GEMM2 (swapped): delta[outcol quad][tilerow] ----
        f32x4 acc2[4][2];
#pragma unroll
        for (int rt = 0; rt < 4; ++rt)
#pragma unroll
            for (int ct = 0; ct < 2; ++ct)
                acc2[rt][ct] = (f32x4){0.f, 0.f, 0.f, 0.f};

        __builtin_amdgcn_s_setprio(1);
#pragma unroll
        for (int ks = 0; ks < 4; ++ks) {
            const bf16x8 wf0 = *(const bf16x8*)(w2w + ks * 1024 + lane * 8);
            const bf16x8 wf1 = *(const bf16x8*)(w2w + ks * 1024 + 512 + lane * 8);
#pragma unroll
            for (int rt = 0; rt < 4; ++rt) {
                const bf16x8 a = *(const bf16x8*)(hs + (rt * 16 + l) * HSS + ks * 32 + g * 8);
                acc2[rt][0] = __builtin_amdgcn_mfma_f32_16x16x32_bf16(wf0, a, acc2[rt][0], 0, 0, 0);
                acc2[rt][1] = __builtin_amdgcn_mfma_f32_16x16x32_bf16(wf1, a, acc2[rt][1], 0, 0, 0);
            }
        }
        __builtin_amdgcn_s_setprio(0);

        // ---- residual: v = x + delta + b2 (vectorized b64 x re-read) ----
        {
            const f32x4 b2q0 = *(const f32x4*)(s_b2 + col0 + g * 4);
            const f32x4 b2q1 = *(const f32x4*)(s_b2 + col0 + 16 + g * 4);
#pragma unroll
            for (int rt = 0; rt < 4; ++rt) {
                const bf16x4 xv0 = *(const bf16x4*)(xs + (rt * 16 + l + 1) * XS + col0 + g * 4);
                const bf16x4 xv1 = *(const bf16x4*)(xs + (rt * 16 + l + 1) * XS + col0 + 16 + g * 4);
#pragma unroll
                for (int i = 0; i < 4; ++i) {
                    acc2[rt][0][i] += b2q0[i] + (float)xv0[i];
                    acc2[rt][1][i] += b2q1[i] + (float)xv1[i];
                }
            }
        }

        // ---- LN partials: per-lane (s, sum v^2) over its 8 cols, per rt ----
#pragma unroll
        for (int rt = 0; rt < 4; ++rt) {
            float s = 0.f, qq = 0.f;
#pragma unroll
            for (int ct = 0; ct < 2; ++ct)
#pragma unroll
                for (int i = 0; i < 4; ++i) {
                    const float v = acc2[rt][ct][i];
                    s += v; qq += v * v;
                }
            ps2[(rt * 16 + l) * PSS + wid * 4 + g] = make_float2(s, qq);
        }
        __syncthreads();  // B4: partials visible; also frees xs/hs for next iter

        // ---- row stats for assigned row (= lane), chunked reads ----
        float mu, rv;
        {
            const f32x4* pp = (const f32x4*)(ps2 + lane * PSS);  // 144B rows
            float S = 0.f, Q = 0.f;
#pragma unroll
            for (int j = 0; j < 4; ++j) {
                const f32x4 e0 = pp[2 * j];
                const f32x4 e1 = pp[2 * j + 1];
                S += (e0[0] + e0[2]) + (e1[0] + e1[2]);
                Q += (e0[1] + e0[3]) + (e1[1] + e1[3]);
            }
            mu = S * (1.f / 128.f);
            const float var = Q * (1.f / 128.f) - mu * mu;
            rv = rsqrtf(var + 1e-5f);
        }

        // ---- normalize + relu in-reg, store f32x4 direct to global ----
        {
            const f32x4 gm0 = *(const f32x4*)(s_gamma + col0 + g * 4);
            const f32x4 gm1 = *(const f32x4*)(s_gamma + col0 + 16 + g * 4);
            const f32x4 bt0 = *(const f32x4*)(s_beta + col0 + g * 4);
            const f32x4 bt1 = *(const f32x4*)(s_beta + col0 + 16 + g * 4);
#pragma unroll
            for (int rt = 0; rt < 4; ++rt) {
                const float mur = __shfl(mu, (lane & 15) + rt * 16);
                const float rvr = __shfl(rv, (lane & 15) + rt * 16);
                float* op = out + (rowbase + n0 + rt * 16 + l) * H + col0;
                f32x4 o0, o1;
#pragma unroll
                for (int i = 0; i < 4; ++i) {
                    o0[i] = fmaxf((acc2[rt][0][i] - mur) * rvr * gm0[i] + bt0[i], 0.f);
                    o1[i] = fmaxf((acc2[rt][1][i] - mur) * rvr * gm1[i] + bt1[i], 0.f);
                }
                *(f32x4*)(op + g * 4)      = o0;
                *(f32x4*)(op + 16 + g * 4) = o1;
            }
        }
    }
}

extern "C" void kernel_launch(void* const* d_in, const int* in_sizes, int n_in,
                              void* d_out, int out_size, void* d_ws, size_t ws_size,
                              hipStream_t stream) {
    const float* x     = (const float*)d_in[0];
    const float* W1    = (const float*)d_in[1];
    const float* b1    = (const float*)d_in[2];
    const float* W2    = (const float*)d_in[3];
    const float* b2    = (const float*)d_in[4];
    const float* gamma = (const float*)d_in[5];
    const float* beta  = (const float*)d_in[6];
    float* out = (float*)d_out;

    // 512 blocks = 2 resident blocks/CU * 256 CUs; grid-stride over 4096 tiles
    cbb_kernel<<<GRID, 256, 0, stream>>>(x, W1, b1, W2, b2, gamma, beta, out);
}